// Round 13
// baseline (189.711 us; speedup 1.0000x reference)
//
#include <hip/hip_runtime.h>

#define H_ 1024
#define NH_ 16
#define HD_ 64
#define B_ 2
#define S_ 2048
#define BS_ 4096

typedef _Float16 half8 __attribute__((ext_vector_type(8)));
typedef _Float16 half4_t __attribute__((ext_vector_type(4)));
typedef float floatx4 __attribute__((ext_vector_type(4)));

#define LOG2E 1.44269504088896f

__device__ __forceinline__ void async_copy16(void* lds, const void* g) {
  __builtin_amdgcn_global_load_lds(
      (const __attribute__((address_space(1))) unsigned int*)g,
      (__attribute__((address_space(3))) unsigned int*)lds, 16, 0, 0);
}

__device__ __forceinline__ half8 cvt8(float4 lo, float4 hi) {
  half8 h;
  h[0] = (_Float16)lo.x; h[1] = (_Float16)lo.y;
  h[2] = (_Float16)lo.z; h[3] = (_Float16)lo.w;
  h[4] = (_Float16)hi.x; h[5] = (_Float16)hi.y;
  h[6] = (_Float16)hi.z; h[7] = (_Float16)hi.w;
  return h;
}

// ---------------- QKV GEMM (fused fp32->fp16 cvt): C = cvt(A) @ cvt(W)^T ---
// grid 768 (1-D, XCD remap: d%8 == y%8) block 256 (4 waves), 128x128 tile,
// BK=32, 32 K-iters. NEW (r13): reads fp32 hs + fp32 Wq/Wk/Wv directly --
// reg-staged (8x float4 loads), scalar-cast to fp16 (same RTN rounding as
// the old cvt_all => bit-identical), ds_write_b128 into a 2-buffer pipeline.
// This DELETES the cvt_all dispatch + its XCD-wide boundary + 50 MB trip.
// Two barriers/tile: barrier1 = __syncthreads (drain is free: only tile-t
// loads outstanding, needed immediately); barrier2 = lgkmcnt(0) + raw
// s_barrier (tile-t+1 loads stay in flight across it -- no vmcnt drain).
__global__ __launch_bounds__(256, 3) void qkv_gemm(
    const float* __restrict__ A, const float* __restrict__ Wq,
    const float* __restrict__ Wk, const float* __restrict__ Wv,
    _Float16* __restrict__ qh, _Float16* __restrict__ kh,
    _Float16* __restrict__ vt) {
  const int d = blockIdx.x;
  const int y = d & 31;        // row-panel; XCD = y % 8
  const int k = d >> 5;        // 0..23
  const int x = k & 7;         // col-panel
  const int z = k >> 3;        // 0=q 1=k 2=v
  const float* W = (z == 0) ? Wq : (z == 1) ? Wk : Wv;
  const int rbase = y * 128;
  const int cbase = x * 128;
  // 33 KB: dbuf A[2][4096] | B[2][4096] halfs; epilogue bounce 128x132
  __shared__ _Float16 SM[16896];
  const int tid = threadIdx.x, lane = tid & 63, w = tid >> 6;
  const int quad = lane >> 4, l16 = lane & 15;
  const int wr = (w >> 1) * 64, wc = (w & 1) * 64;

  floatx4 zero = {0.f, 0.f, 0.f, 0.f};
  floatx4 acc[4][4];
#pragma unroll
  for (int i = 0; i < 4; ++i)
#pragma unroll
    for (int j = 0; j < 4; ++j) acc[i][j] = zero;

  // staging geometry identical to r12 (row tid>>2 (+64), slot tid&3,
  // source col-chunk pre-swizzled so reads use quad^rsw)
  const int srow = tid >> 2;   // 0..63 (+64)
  const int pslot = tid & 3;
  const int sslot = pslot ^ ((srow >> 1) & 3);
  const float* Ag = A + (size_t)(rbase + srow) * H_ + sslot * 8;
  const float* Bg = W + (size_t)(cbase + srow) * H_ + sslot * 8;

  float4 ra[4], rb[4];
  auto LOAD = [&](int t) {
    const int k0 = t * 32;
    ra[0] = *(const float4*)(Ag + k0);
    ra[1] = *(const float4*)(Ag + k0 + 4);
    ra[2] = *(const float4*)(Ag + (size_t)64 * H_ + k0);
    ra[3] = *(const float4*)(Ag + (size_t)64 * H_ + k0 + 4);
    rb[0] = *(const float4*)(Bg + k0);
    rb[1] = *(const float4*)(Bg + k0 + 4);
    rb[2] = *(const float4*)(Bg + (size_t)64 * H_ + k0);
    rb[3] = *(const float4*)(Bg + (size_t)64 * H_ + k0 + 4);
  };
  auto WRITE = [&](int s) {
    _Float16* ab = &SM[s * 4096 + tid * 8];
    _Float16* bb = &SM[8192 + s * 4096 + tid * 8];
    *(half8*)ab = cvt8(ra[0], ra[1]);
    *(half8*)(ab + 2048) = cvt8(ra[2], ra[3]);
    *(half8*)bb = cvt8(rb[0], rb[1]);
    *(half8*)(bb + 2048) = cvt8(rb[2], rb[3]);
  };

  const int rsw = (l16 >> 1) & 3;  // (row>>1)&3 of fragment rows
  auto COMPUTE = [&](int s) {
    const _Float16* Ap = &SM[s * 4096];
    const _Float16* Bp = &SM[8192 + s * 4096];
    half8 af[4], bf[4];
#pragma unroll
    for (int t = 0; t < 4; ++t)
      af[t] = *(const half8*)&Ap[(wr + t * 16 + l16) * 32 + (quad ^ rsw) * 8];
#pragma unroll
    for (int t = 0; t < 4; ++t)
      bf[t] = *(const half8*)&Bp[(wc + t * 16 + l16) * 32 + (quad ^ rsw) * 8];
    __builtin_amdgcn_s_setprio(1);
#pragma unroll
    for (int i = 0; i < 4; ++i)
#pragma unroll
      for (int j = 0; j < 4; ++j)
        acc[i][j] = __builtin_amdgcn_mfma_f32_16x16x32_f16(af[i], bf[j],
                                                           acc[i][j], 0, 0, 0);
    __builtin_amdgcn_s_setprio(0);
  };

  LOAD(0);
  for (int t = 0; t < 32; ++t) {
    // barrier 1: fences COMPUTE(t-2)'s reads of buf[t&1] before overwrite.
    // Implicit vmcnt(0) drain only covers LOAD(t) -- consumed right after.
    __syncthreads();
    WRITE(t & 1);                // compiler waits ra/rb via register deps
    if (t < 31) LOAD(t + 1);     // flies across barrier 2 + COMPUTE
    // barrier 2: ds_writes visible; do NOT drain vmcnt (t+1 loads in flight)
    asm volatile("s_waitcnt lgkmcnt(0)" ::: "memory");
    __builtin_amdgcn_s_barrier();
    __builtin_amdgcn_sched_barrier(0);
    COMPUTE(t & 1);
  }

  // ---- coalesced epilogue via LDS bounce (pitch 132 halfs) [r12] ----
  __syncthreads();  // all COMPUTE LDS reads done before reuse
  const int PAD = 132;
  const int b = rbase >> 11, sl_base = rbase & (S_ - 1);
  if (z != 2) {
    const float scale = (z == 0) ? LOG2E : 1.0f;
#pragma unroll
    for (int i = 0; i < 4; ++i) {
      int s0 = wr + i * 16 + quad * 4;
#pragma unroll
      for (int j = 0; j < 4; ++j) {
        int c = wc + j * 16 + l16;
#pragma unroll
        for (int r = 0; r < 4; ++r) {
          float xx = acc[i][j][r];
          xx = ((xx > 0.f) ? (xx + 1.f) : __expf(xx)) * scale;
          SM[(s0 + r) * PAD + c] = (_Float16)xx;
        }
      }
    }
    __syncthreads();
    _Float16* outp = (z == 0) ? qh : kh;
#pragma unroll
    for (int k2 = 0; k2 < 8; ++k2) {
      int c2 = tid + k2 * 256;
      int s = c2 >> 4, part = c2 & 15;
      int col = cbase + part * 8;
      int h = col >> 6, dd = col & 63;
      half8 vvv = *(const half8*)&SM[s * PAD + part * 8];
      *(half8*)&outp[((size_t)(b * NH_ + h) * S_ + sl_base + s) * HD_ + dd] = vvv;
    }
  } else {
    // v: transposed bounce SM[c][s]
#pragma unroll
    for (int i = 0; i < 4; ++i) {
      int s0 = wr + i * 16 + quad * 4;
#pragma unroll
      for (int j = 0; j < 4; ++j) {
        int c = wc + j * 16 + l16;
#pragma unroll
        for (int r = 0; r < 4; ++r)
          SM[c * PAD + s0 + r] = (_Float16)acc[i][j][r];
      }
    }
    __syncthreads();
#pragma unroll
    for (int k2 = 0; k2 < 8; ++k2) {
      int c2 = tid + k2 * 256;
      int c = c2 >> 4, part = c2 & 15;
      int col = cbase + c;
      int h = col >> 6, dd = col & 63;
      half8 vvv = *(const half8*)&SM[c * PAD + part * 8];
      *(half8*)&vt[((size_t)(b * NH_ + h) * HD_ + dd) * S_ + sl_base + part * 8] = vvv;
    }
  }
}

// ---------------- Flash attention ------------------------------------------
// grid 512 (1-D, XCD-locality remap: d%8 == bh%8) block 256 (4 waves,
// 32 q-rows), BC=128. Swapped-operand scheme; K/V double-buffered via
// global_load_lds; ONE barrier per tile. [r12, byte-identical]
__global__ __launch_bounds__(256, 2) void flash_attn(
    const _Float16* __restrict__ qh, const _Float16* __restrict__ kh,
    const _Float16* __restrict__ vt, const int* __restrict__ mask,
    _Float16* __restrict__ attn_out) {
  const int dd = blockIdx.x;
  const int bh = dd & 31, b = bh >> 4, h = bh & 15;  // XCD = bh % 8
  const int qbase = (dd >> 5) * 128;
  const int tid = threadIdx.x, w = tid >> 6, lane = tid & 63;
  const int quad = lane >> 4, l16 = lane & 15;

  __shared__ _Float16 Kt[2][128 * 64];  // [key][d], slot = (d>>3)^(key&7)
  __shared__ _Float16 Vt[2][64 * 128];  // [d][key], slot = (key>>3)^(d&15)

  const _Float16* Q = qh + (size_t)bh * (S_ * HD_);
  const _Float16* K = kh + (size_t)bh * (S_ * HD_);
  const _Float16* Vg = vt + (size_t)bh * (HD_ * S_);
  const int* Mb = mask + b * S_;

  // Q B-fragments (2 row-groups of 16 q) in registers for the whole kernel
  half8 qf[2][2];
#pragma unroll
  for (int g = 0; g < 2; ++g) {
    int qr = qbase + w * 32 + g * 16 + l16;
    qf[g][0] = *(const half8*)&Q[qr * 64 + quad * 8];
    qf[g][1] = *(const half8*)&Q[qr * 64 + 32 + quad * 8];
  }

  floatx4 zero = {0.f, 0.f, 0.f, 0.f};
  floatx4 o[2][4];  // O^T[d = ct2*16 + quad*4 + r][q = l16 (group g)]
#pragma unroll
  for (int g = 0; g < 2; ++g)
#pragma unroll
    for (int i = 0; i < 4; ++i) o[g][i] = zero;
  float mi[2] = {-3e38f, -3e38f}, li[2] = {0.f, 0.f};

  // staging constants
  const int krow_off = lane >> 3;             // 0..7
  const int kslot = lane & 7;
  const int kchunk = kslot ^ (krow_off & 7);
  const int vrow_off = lane >> 4;             // 0..3
  const int vslot = lane & 15;

  // prologue: stage tile 0 into buffer 0
  {
#pragma unroll
    for (int u = 0; u < 4; ++u) {
      int kl = w * 32 + u * 8;
      async_copy16(&Kt[0][kl * 64], K + (size_t)(kl + krow_off) * 64 + kchunk * 8);
    }
#pragma unroll
    for (int u = 0; u < 4; ++u) {
      int d0 = w * 16 + u * 4 + vrow_off;
      int c0 = vslot ^ (d0 & 15);
      async_copy16(&Vt[0][(w * 16 + u * 4) * 128], Vg + (size_t)d0 * S_ + c0 * 8);
    }
  }

  for (int kt = 0; kt < S_ / 128; ++kt) {
    const int key0 = kt * 128;
    const int buf = kt & 1;
    // barrier: compiler-inserted vmcnt(0) drains our DMA (issued a full tile
    // ago -> latency hidden); barrier makes all waves' DMA visible.
    __syncthreads();
    // prefetch next tile into the other buffer
    if (kt < S_ / 128 - 1) {
      const int key1 = key0 + 128;
#pragma unroll
      for (int u = 0; u < 4; ++u) {
        int kl = w * 32 + u * 8;
        async_copy16(&Kt[buf ^ 1][kl * 64],
                     K + (size_t)(key1 + kl + krow_off) * 64 + kchunk * 8);
      }
#pragma unroll
      for (int u = 0; u < 4; ++u) {
        int d0 = w * 16 + u * 4 + vrow_off;
        int c0 = vslot ^ (d0 & 15);
        async_copy16(&Vt[buf ^ 1][(w * 16 + u * 4) * 128],
                     Vg + (size_t)d0 * S_ + key1 + c0 * 8);
      }
    }
    int m0 = Mb[key0 + lane];
    int m1 = Mb[key0 + 64 + lane];

    const _Float16* Kb = &Kt[buf][0];
    const _Float16* Vb = &Vt[buf][0];

    // S^T tile: mfma(A=K-frag, B=Q-frag) -> S^T[key=ct*16+quad*4+r][q=l16]
    floatx4 sa[2][8];
#pragma unroll
    for (int g = 0; g < 2; ++g)
#pragma unroll
      for (int ct = 0; ct < 8; ++ct) sa[g][ct] = zero;
    {
      int s0 = quad ^ (l16 & 7);
      int s1 = (4 + quad) ^ (l16 & 7);
#pragma unroll
      for (int ct = 0; ct < 8; ++ct) {
        int key = ct * 16 + l16;
        half8 bf0 = *(half8*)&Kb[key * 64 + s0 * 8];
        half8 bf1 = *(half8*)&Kb[key * 64 + s1 * 8];
        sa[0][ct] = __builtin_amdgcn_mfma_f32_16x16x32_f16(bf0, qf[0][0], sa[0][ct], 0, 0, 0);
        sa[0][ct] = __builtin_amdgcn_mfma_f32_16x16x32_f16(bf1, qf[0][1], sa[0][ct], 0, 0, 0);
        sa[1][ct] = __builtin_amdgcn_mfma_f32_16x16x32_f16(bf0, qf[1][0], sa[1][ct], 0, 0, 0);
        sa[1][ct] = __builtin_amdgcn_mfma_f32_16x16x32_f16(bf1, qf[1][1], sa[1][ct], 0, 0, 0);
      }
    }
    // masking (fast path: tile fully unmasked). key = ct*16 + quad*4 + r
    if (__any((m0 == 0) || (m1 == 0))) {
#pragma unroll
      for (int ct = 0; ct < 8; ++ct)
#pragma unroll
        for (int r = 0; r < 4; ++r)
          if (Mb[key0 + ct * 16 + quad * 4 + r] == 0) {
            sa[0][ct][r] = -1e30f;
            sa[1][ct][r] = -1e30f;
          }
    }
    // online softmax per q-column (in-lane over 32 logits + 2 shuffles)
#pragma unroll
    for (int g = 0; g < 2; ++g) {
      float mx = sa[g][0][0];
#pragma unroll
      for (int ct = 0; ct < 8; ++ct)
#pragma unroll
        for (int r = 0; r < 4; ++r) mx = fmaxf(mx, sa[g][ct][r]);
      mx = fmaxf(mx, __shfl_xor(mx, 16));
      mx = fmaxf(mx, __shfl_xor(mx, 32));
      float mn = fmaxf(mi[g], mx);
      float alpha = __builtin_amdgcn_exp2f(mi[g] - mn);
      mi[g] = mn;
      float rs = 0.f;
#pragma unroll
      for (int ct = 0; ct < 8; ++ct)
#pragma unroll
        for (int r = 0; r < 4; ++r) {
          float p = __builtin_amdgcn_exp2f(sa[g][ct][r] - mn);
          sa[g][ct][r] = p;
          rs += p;
        }
      rs += __shfl_xor(rs, 16);
      rs += __shfl_xor(rs, 32);
      li[g] = li[g] * alpha + rs;
#pragma unroll
      for (int ct2 = 0; ct2 < 4; ++ct2) {
        o[g][ct2][0] *= alpha; o[g][ct2][1] *= alpha;
        o[g][ct2][2] *= alpha; o[g][ct2][3] *= alpha;
      }
    }
    // PV: O^T += mfma(A=V^T-frag, B=P^T-frag) over 8 key-chunks of 16.
    // P^T C-layout (key=quad*4+r) IS the 16x16x16 B-operand layout.
#pragma unroll
    for (int ct = 0; ct < 8; ++ct) {
      half4_t p0, p1;
#pragma unroll
      for (int r = 0; r < 4; ++r) {
        p0[r] = (_Float16)sa[0][ct][r];
        p1[r] = (_Float16)sa[1][ct][r];
      }
      int chunk = (2 * ct + (quad >> 1)) ^ l16;  // key-chunk swizzled by d&15
      int off = chunk * 8 + (quad & 1) * 4;
#pragma unroll
      for (int ct2 = 0; ct2 < 4; ++ct2) {
        int dx = ct2 * 16 + l16;
        half4_t vf = *(half4_t*)&Vb[dx * 128 + off];
        o[0][ct2] = __builtin_amdgcn_mfma_f32_16x16x16f16(vf, p0, o[0][ct2], 0, 0, 0);
        o[1][ct2] = __builtin_amdgcn_mfma_f32_16x16x16f16(vf, p1, o[1][ct2], 0, 0, 0);
      }
    }
  }
  // epilogue: normalize, store (B, S, H) fp16 — half4 stores (d contiguous)
#pragma unroll
  for (int g = 0; g < 2; ++g) {
    float inv = 1.0f / li[g];
    int row = qbase + w * 32 + g * 16 + l16;
#pragma unroll
    for (int ct2 = 0; ct2 < 4; ++ct2) {
      half4_t pk;
#pragma unroll
      for (int r = 0; r < 4; ++r) pk[r] = (_Float16)(o[g][ct2][r] * inv);
      int dx = ct2 * 16 + quad * 4;
      *(half4_t*)&attn_out[((size_t)(b * S_ + row)) * H_ + h * HD_ + dx] = pk;
    }
  }
}

// ---------------- Output GEMM (fused Wo cvt): out = AO @ cvt(Wo)^T ---------
// grid 512 (1-D, XCD remap: d%8 == y%8) block 256: 128x64 tiles, BK=64,
// 16 K-iters. NEW (r13): reads ao fp16 + Wo fp32 directly (reg-staged,
// B converted in-flight) -- removes the Wo leg of the deleted cvt_all.
// Two-barrier double-buffer, same discipline as qkv_gemm. fp32 LDS-bounce
// epilogue -> coalesced float4 stores [r12].
__global__ __launch_bounds__(256, 2) void out_gemm(
    const _Float16* __restrict__ A, const float* __restrict__ W,
    float* __restrict__ out) {
  const int d = blockIdx.x;
  const int y = d & 31;        // row-panel; XCD = y % 8
  const int x = d >> 5;        // 0..15
  const int rbase = y * 128;
  const int cbase = x * 64;
  // 48 KB: dbuf A[2][8192] | B[2][4096] halfs; fp32 bounce 128x68x4B=34.8KB
  __shared__ _Float16 SM[24576];
  const int tid = threadIdx.x, lane = tid & 63, w = tid >> 6;
  const int quad = lane >> 4, l16 = lane & 15;

  floatx4 zero = {0.f, 0.f, 0.f, 0.f};
  floatx4 acc[2][4];
#pragma unroll
  for (int i = 0; i < 2; ++i)
#pragma unroll
    for (int j = 0; j < 4; ++j) acc[i][j] = zero;

  const int srow = tid >> 3;   // 0..31 (+u*32)
  const int pslot = tid & 7;
  const int sslot = pslot ^ (srow & 7);
  const _Float16* Ag = A + (size_t)(rbase + srow) * H_ + sslot * 8;
  const float* Bg = W + (size_t)(cbase + srow) * H_ + sslot * 8;

  half8 qa[4];
  float4 rb[4];
  auto LOAD = [&](int t) {
    const int k0 = t * 64;
#pragma unroll
    for (int u = 0; u < 4; ++u)
      qa[u] = *(const half8*)(Ag + (size_t)(u * 32) * H_ + k0);
    rb[0] = *(const float4*)(Bg + k0);
    rb[1] = *(const float4*)(Bg + k0 + 4);
    rb[2] = *(const float4*)(Bg + (size_t)32 * H_ + k0);
    rb[3] = *(const float4*)(Bg + (size_t)32 * H_ + k0 + 4);
  };
  auto WRITE = [&](int s) {
    _Float16* ab = &SM[s * 8192 + tid * 8];
    _Float16* bb = &SM[16384 + s * 4096 + tid * 8];
#pragma unroll
    for (int u = 0; u < 4; ++u) *(half8*)(ab + u * 2048) = qa[u];
    *(half8*)bb = cvt8(rb[0], rb[1]);
    *(half8*)(bb + 2048) = cvt8(rb[2], rb[3]);
  };

  const int rsw = l16 & 7;  // row&7 of fragment rows (base bits are 0 mod 8)
  auto COMPUTE = [&](int s) {
    const _Float16* Ap = &SM[s * 8192];
    const _Float16* Bp = &SM[16384 + s * 4096];
    half8 af[2][2], bf[4][2];
#pragma unroll
    for (int i = 0; i < 2; ++i)
#pragma unroll
      for (int hh = 0; hh < 2; ++hh)
        af[i][hh] = *(const half8*)&Ap[(w * 32 + i * 16 + l16) * 64 +
                                       (((hh * 4 + quad) ^ rsw) * 8)];
#pragma unroll
    for (int j = 0; j < 4; ++j)
#pragma unroll
      for (int hh = 0; hh < 2; ++hh)
        bf[j][hh] = *(const half8*)&Bp[(j * 16 + l16) * 64 +
                                       (((hh * 4 + quad) ^ rsw) * 8)];
    __builtin_amdgcn_s_setprio(1);
#pragma unroll
    for (int i = 0; i < 2; ++i)
#pragma unroll
      for (int j = 0; j < 4; ++j) {
        acc[i][j] = __builtin_amdgcn_mfma_f32_16x16x32_f16(af[i][0], bf[j][0],
                                                           acc[i][j], 0, 0, 0);
        acc[i][j] = __builtin_amdgcn_mfma_f32_16x16x32_f16(af[i][1], bf[j][1],
                                                           acc[i][j], 0, 0, 0);
      }
    __builtin_amdgcn_s_setprio(0);
  };

  LOAD(0);
  for (int t = 0; t < 16; ++t) {
    __syncthreads();
    WRITE(t & 1);
    if (t < 15) LOAD(t + 1);
    asm volatile("s_waitcnt lgkmcnt(0)" ::: "memory");
    __builtin_amdgcn_s_barrier();
    __builtin_amdgcn_sched_barrier(0);
    COMPUTE(t & 1);
  }

  // ---- coalesced fp32 epilogue via LDS bounce (pitch 68 floats) [r12] ----
  __syncthreads();  // all COMPUTE LDS reads done before reuse
  float* FB = (float*)SM;
  const int FPAD = 68;
#pragma unroll
  for (int i = 0; i < 2; ++i) {
    int s0 = w * 32 + i * 16 + quad * 4;
#pragma unroll
    for (int j = 0; j < 4; ++j) {
      int c = j * 16 + l16;
#pragma unroll
      for (int r = 0; r < 4; ++r)
        FB[(s0 + r) * FPAD + c] = acc[i][j][r];
    }
  }
  __syncthreads();
#pragma unroll
  for (int k2 = 0; k2 < 8; ++k2) {
    int c2 = tid + k2 * 256;
    int s = c2 >> 4, part = c2 & 15;
    *(float4*)&out[(size_t)(rbase + s) * H_ + cbase + part * 4] =
        *(float4*)&FB[s * FPAD + part * 4];
  }
}

extern "C" void kernel_launch(void* const* d_in, const int* in_sizes, int n_in,
                              void* d_out, int out_size, void* d_ws,
                              size_t ws_size, hipStream_t stream) {
  const float* hs = (const float*)d_in[0];
  const int* mask = (const int*)d_in[1];
  const float* Wq = (const float*)d_in[2];
  const float* Wk = (const float*)d_in[3];
  const float* Wv = (const float*)d_in[4];
  const float* Wo = (const float*)d_in[5];
  float* out = (float*)d_out;

  _Float16* p = (_Float16*)d_ws;
  _Float16* q_h = p;  p += (size_t)BS_ * H_;
  _Float16* k_h = p;  p += (size_t)BS_ * H_;
  _Float16* v_t = p;  p += (size_t)BS_ * H_;
  _Float16* ao_h = p; p += (size_t)BS_ * H_;

  qkv_gemm<<<768, 256, 0, stream>>>(hs, Wq, Wk, Wv, q_h, k_h, v_t);
  flash_attn<<<512, 256, 0, stream>>>(q_h, k_h, v_t, mask, ao_h);
  out_gemm<<<512, 256, 0, stream>>>(ao_h, Wo, out);
}